// Round 7
// baseline (366.366 us; speedup 1.0000x reference)
//
#include <hip/hip_runtime.h>
#include <cstdint>

typedef short short8 __attribute__((ext_vector_type(8)));
typedef float f32x4 __attribute__((ext_vector_type(4)));

#define LDS_AS3(p) ((__attribute__((address_space(3))) unsigned*)(p))
#define GLB_AS1(p) ((const __attribute__((address_space(1))) unsigned*)(p))

// fp32 -> bf16 (round-to-nearest-even), two packed into a u32
__device__ inline unsigned bfpack(float a, float b) {
    union { float f; unsigned u; } ua, ub;
    ua.f = a; ub.f = b;
    unsigned lo = (ua.u + 0x7FFFu + ((ua.u >> 16) & 1u)) >> 16;
    unsigned hi = (ub.u + 0x7FFFu + ((ub.u >> 16) & 1u)) & 0xFFFF0000u;
    return lo | hi;
}
__device__ inline unsigned short bf16of(float a) { return (unsigned short)bfpack(a, 0.0f); }
__device__ inline float bf2f(unsigned short s) {
    union { unsigned u; float f; } x; x.u = (unsigned)s << 16; return x.f;
}

// ---------------- prepass: convert X to bf16 (same [.,448,512] layout) ------
__global__ __launch_bounds__(256)
void cvt_x(const float* __restrict__ X, unsigned short* __restrict__ XB)
{
    const int g = blockIdx.x * 256 + threadIdx.x;
    const float4 v0 = *(const float4*)(X + (size_t)g * 8);
    const float4 v1 = *(const float4*)(X + (size_t)g * 8 + 4);
    uint4 u;
    u.x = bfpack(v0.x, v0.y); u.y = bfpack(v0.z, v0.w);
    u.z = bfpack(v1.x, v1.y); u.w = bfpack(v1.z, v1.w);
    *(uint4*)(XB + (size_t)g * 8) = u;
}

// ------------- prepass: convert + transpose W[512][N] -> WT[N][512] bf16 ----
template <int N>
__global__ __launch_bounds__(256)
void cvt_w(const float* __restrict__ W, unsigned short* __restrict__ WT)
{
    const int g = blockIdx.x * 256 + threadIdx.x;
    if (g >= N * 64) return;
    const int n = g % N, d8 = g / N;
    const float* p = W + (size_t)d8 * 8 * N + n;
    uint4 u;
    u.x = bfpack(p[0],             p[(size_t)N]);
    u.y = bfpack(p[2 * (size_t)N], p[3 * (size_t)N]);
    u.z = bfpack(p[4 * (size_t)N], p[5 * (size_t)N]);
    u.w = bfpack(p[6 * (size_t)N], p[7 * (size_t)N]);
    *(uint4*)(WT + (size_t)n * 512 + d8 * 8) = u;
}

// ------------- 256x256 8-wave 4-phase GEMM + closed-form scatter ------------
// BM=BN=256, BK=64, 8 waves (2M x 4N), per-wave C = 128x64.
// LDS [2 dbuf][2 half][128][64] per operand (128 KB), 8-way XOR slot swizzle
// on the GLOBAL source (rule #21), linear gload_lds dest.
// RACE-SAFE staging (R5 fix): readers occupy BOTH halves of buf every phase,
// so only buf^1's slots are free. Stage kt+1 at ph0 (A.h0,B.h0) and ph1
// (A.h1,B.h1) -- earliest legal (buf^1's last readers were pre-barrier at
// kt-1/ph3) -- then one vmcnt(0) at ph3, ~2.5 phases after last issue.
template <int MODE>
__global__ __launch_bounds__(512, 2)
void gemm_scatter(const unsigned short* __restrict__ XB,
                  const unsigned short* __restrict__ WT,
                  const float* __restrict__ BIAS, float* __restrict__ Y,
                  const unsigned short* __restrict__ EXTI,
                  unsigned short* __restrict__ EXTO)
{
    constexpr int K_L  = (MODE == 0) ? 64 : (MODE == 1) ? 128 : 256;
    constexpr int LOGK = (MODE == 0) ? 6  : (MODE == 1) ? 7   : 8;
    constexpr int N    = (MODE == 0) ? 1180 : (MODE == 1) ? 2881 : 1153;
    constexpr int XOFF = (MODE == 0) ? 0 : (MODE == 1) ? 64 : 192;
    constexpr int NT   = (N + 255) / 256;

    __shared__ __align__(16) unsigned short lA[2 * 2 * 128 * 64];  // 64 KB
    __shared__ __align__(16) unsigned short lB[2 * 2 * 128 * 64];  // 64 KB

    const int t    = threadIdx.x;            // 0..511
    const int lane = t & 63;
    const int wv   = t >> 6;                 // 0..7
    const int wr   = wv >> 2;                // m-wave 0..1
    const int wc   = wv & 3;                 // n-wave 0..3
    const int kq   = lane >> 4;              // k quarter 0..3
    const int lr16 = lane & 15;

    // bijective XCD-chunk swizzle (grids divisible by 8); N-minor order
    const int cpx = (int)gridDim.x >> 3;
    const int wg  = (blockIdx.x & 7) * cpx + (blockIdx.x >> 3);
    const int nt  = wg % NT;
    const int mt  = wg / NT;
    const int m0  = mt * 256;
    const int n0  = nt * 256;

    f32x4 acc[8][4] = {};

    // stage one half-tile (128 rows x 64 k bf16 = 16 KB): 2 gload_lds/thread.
    // physical chunk (row, p) holds logical k-slot l = p ^ (row & 7).
    auto stageHalf = [&](int buf, int op /*0=A,1=B*/, int half, int kt) {
        #pragma unroll
        for (int rnd = 0; rnd < 2; ++rnd) {
            const int c   = rnd * 512 + t;       // 0..1023
            const int row = c >> 3;
            const int l   = (c & 7) ^ (row & 7); // logical slot (8 bf16 each)
            const unsigned short* gp;
            if (op == 0) {
                const int m = m0 + half * 128 + row;
                const int b = m >> LOGK, kd = m & (K_L - 1);
                gp = XB + ((size_t)(b * 448 + XOFF + kd) << 9) + kt * 64 + l * 8;
            } else {
                int gc = n0 + half * 128 + row; if (gc > N - 1) gc = N - 1;
                gp = WT + (size_t)gc * 512 + kt * 64 + l * 8;
            }
            unsigned short* dst = (op ? lB : lA) + (size_t)(buf * 2 + half) * (128 * 64) + c * 8;
            __builtin_amdgcn_global_load_lds(GLB_AS1(gp), LDS_AS3(dst), 16, 0, 0);
        }
    };

    // ---- prologue: all 4 half-tiles of kt0 into buf0, full retire ---------
    stageHalf(0, 0, 0, 0);
    stageHalf(0, 1, 0, 0);
    stageHalf(0, 0, 1, 0);
    stageHalf(0, 1, 1, 0);
    asm volatile("s_waitcnt vmcnt(0)" ::: "memory");
    __builtin_amdgcn_s_barrier();

    // ---- K loop: 8 K-tiles of 64, 4 phases each ---------------------------
    #pragma unroll 1
    for (int kt = 0; kt < 8; ++kt) {
        const int buf = kt & 1;
        const char* Abase = (const char*)lA + (size_t)(buf * 2 + wr) * (128 * 128);
        const char* Bbase = (const char*)lB + (size_t)(buf * 2 + (wc >> 1)) * (128 * 128);

        #pragma unroll
        for (int ph = 0; ph < 4; ++ph) {
            const int mq = ph >> 1, ks = ph & 1;

            short8 af[4], bf[4];
            #pragma unroll
            for (int mi = 0; mi < 4; ++mi) {
                const int row  = mq * 64 + mi * 16 + lr16;
                const int slot = (ks * 4 + kq) ^ (row & 7);
                af[mi] = *(const short8*)(Abase + row * 128 + slot * 16);
            }
            #pragma unroll
            for (int ni = 0; ni < 4; ++ni) {
                const int row  = (wc & 1) * 64 + ni * 16 + lr16;
                const int slot = (ks * 4 + kq) ^ (row & 7);
                bf[ni] = *(const short8*)(Bbase + row * 128 + slot * 16);
            }

            // stage kt+1 into buf^1 only (free slots); retire at ph3
            if (ph == 0) {
                if (kt + 1 < 8) { stageHalf(buf ^ 1, 0, 0, kt + 1);
                                  stageHalf(buf ^ 1, 1, 0, kt + 1); }
            } else if (ph == 1) {
                if (kt + 1 < 8) { stageHalf(buf ^ 1, 0, 1, kt + 1);
                                  stageHalf(buf ^ 1, 1, 1, kt + 1); }
            } else if (ph == 3) {
                asm volatile("s_waitcnt vmcnt(0)" ::: "memory");
            }

            __builtin_amdgcn_s_barrier();
            __builtin_amdgcn_s_setprio(1);
            #pragma unroll
            for (int mi = 0; mi < 4; ++mi)
                #pragma unroll
                for (int ni = 0; ni < 4; ++ni)
                    acc[mq * 4 + mi][ni] = __builtin_amdgcn_mfma_f32_16x16x32_bf16(
                        af[mi], bf[ni], acc[mq * 4 + mi][ni], 0, 0, 0);
            __builtin_amdgcn_s_setprio(0);
            __builtin_amdgcn_s_barrier();
        }
    }

    // ---- epilogue: bias + closed-form scatter (EXT fusion, verified R4) ---
    #pragma unroll
    for (int ni = 0; ni < 4; ++ni) {
        const int n = n0 + wc * 64 + ni * 16 + lr16;
        if (n >= N) continue;
        const float bias = BIAS[n];
        #pragma unroll
        for (int mi = 0; mi < 8; ++mi) {
            #pragma unroll
            for (int r = 0; r < 4; ++r) {
                const int m  = m0 + wr * 128 + mi * 16 + kq * 4 + r;
                const int b  = m >> LOGK;
                const int kd = m & (K_L - 1);
                const float v = acc[mi][ni][r] + bias;
                float* yb = Y + (size_t)b * 370816;
                if constexpr (MODE == 0) {
                    if (n < 27)       yb[kd * 27 + n] = v;
                    else if (n == 27) yb[1728 + kd]   = v;
                    else EXTO[((size_t)(b * 64 + kd)) * 1152 + (n - 28)] = bf16of(v);
                } else if constexpr (MODE == 1) {
                    if (n < 576) {
                        const float e = bf2f(EXTI[((size_t)(b * 64 + n / 9)) * 1152 + kd * 9 + n % 9]);
                        yb[1792 + kd * 576 + n] = 0.5f * (v + e);
                    } else if (n == 576) yb[75520 + kd] = 0.5f * v;
                    else EXTO[((size_t)(b * 128 + kd)) * 2304 + (n - 577)] = bf16of(v);
                } else {
                    if (n < 1152) {
                        const float e = bf2f(EXTI[((size_t)(b * 128 + n / 9)) * 2304 + kd * 9 + n % 9]);
                        yb[75648 + kd * 1152 + n] = v + e;
                    } else yb[370560 + kd] = v;
                }
            }
        }
    }
}

extern "C" void kernel_launch(void* const* d_in, const int* in_sizes, int n_in,
                              void* d_out, int out_size, void* d_ws, size_t ws_size,
                              hipStream_t stream)
{
    const float* x  = (const float*)d_in[0];
    const float* W0 = (const float*)d_in[1];
    const float* b0 = (const float*)d_in[2];
    const float* W1 = (const float*)d_in[3];
    const float* b1 = (const float*)d_in[4];
    const float* W2 = (const float*)d_in[5];
    const float* b2 = (const float*)d_in[6];
    float* y = (float*)d_out;

    // ws (bf16): XB[128*448*512] | WT0 | WT1 | WT2 | EXT0[128*64*1152] | EXT1[128*128*2304]
    unsigned short* XB   = (unsigned short*)d_ws;
    unsigned short* WT0  = XB   + (size_t)128 * 448 * 512;
    unsigned short* WT1  = WT0  + (size_t)1180 * 512;
    unsigned short* WT2  = WT1  + (size_t)2881 * 512;
    unsigned short* EXT0 = WT2  + (size_t)1153 * 512;
    unsigned short* EXT1 = EXT0 + (size_t)128 * 64 * 1152;

    cvt_x<<<dim3(14336), 256, 0, stream>>>(x, XB);
    cvt_w<1180><<<dim3((1180 * 64 + 255) / 256), 256, 0, stream>>>(W0, WT0);
    cvt_w<2881><<<dim3((2881 * 64 + 255) / 256), 256, 0, stream>>>(W1, WT1);
    cvt_w<1153><<<dim3((1153 * 64 + 255) / 256), 256, 0, stream>>>(W2, WT2);

    // grids: (M/256) * ceil(N/256); stream order carries the EXT dependency
    gemm_scatter<0><<<dim3(32 * 5),   512, 0, stream>>>(XB, WT0, b0, y, nullptr, EXT0);
    gemm_scatter<1><<<dim3(64 * 12),  512, 0, stream>>>(XB, WT1, b1, y, EXT0, EXT1);
    gemm_scatter<2><<<dim3(128 * 5),  512, 0, stream>>>(XB, WT2, b2, y, EXT1, nullptr);
}